// Round 14
// baseline (162.060 us; speedup 1.0000x reference)
//
#include <hip/hip_runtime.h>

// Grid: 512x512 nodes, idx = row*512 + col. h = 1/511.
// m_in = [s_dst, deg_dst, s_src, deg_src, ea_x, ea_y] @ W1 -> tanh -> @ W2
// g(s)[n] = (1/deg_n) * sum_incoming(msg) + b2
//
// R13 = R12 with the interior-classification fix: interior fast path needs
// deg==4 for the node AND all 4 neighbors. Grid-rows 1/510 have neighbors in
// rows 0/511 (degree 3), so interior is brow in [2,509] (was [1,510] — that
// off-by-one caused R12's absmax 0.59 fail). Col side safe: segs 1..6 =>
// neighbors cols 63..448, all degree 4.
// Interior (74.6% of blocks): hb calc + degree loads folded into LDS bias,
// v_dot2_f32_f16 accumulate (f32, no boundary mask). Boundary: R11 path.
// Activations: grad3 = lambda-Pade[3/2] (err 0.013, lambda in W2);
// final = Hermite cubic (outputs damped by NU=0.01).

#define GW    512
#define GN    (GW * GW)
#define HID   64
#define SPLIT 4
#define JPT   (HID / SPLIT)    // 16 hidden units per thread
#define NUC   0.01f
#define LAM   0.9873f          // Pade error-centering, folded into c0/c1

typedef _Float16 h2 __attribute__((ext_vector_type(2)));

__device__ __forceinline__ float h2f(h2 x) { return __builtin_bit_cast(float, x); }
__device__ __forceinline__ h2 f2h(float x) { return __builtin_bit_cast(h2, x); }

// Inline-asm packed f16 helpers (clang won't form v_pk_* from ext_vector on
// gfx950 — R3 vs R4 evidence). Operands proxied as 32-bit floats.
__device__ __forceinline__ h2 pk_fma(h2 a, h2 b, h2 c) {
    float d, fa = h2f(a), fb = h2f(b), fc = h2f(c);
    asm("v_pk_fma_f16 %0, %1, %2, %3" : "=v"(d) : "v"(fa), "v"(fb), "v"(fc));
    return f2h(d);
}
__device__ __forceinline__ h2 pk_nfma(h2 a, h2 b, h2 c) {   // (-a)*b + c
    float d, fa = h2f(a), fb = h2f(b), fc = h2f(c);
    asm("v_pk_fma_f16 %0, %1, %2, %3 neg_lo:[1,0,0] neg_hi:[1,0,0]"
        : "=v"(d) : "v"(fa), "v"(fb), "v"(fc));
    return f2h(d);
}
__device__ __forceinline__ h2 pk_mul(h2 a, h2 b) {
    float d, fa = h2f(a), fb = h2f(b);
    asm("v_pk_mul_f16 %0, %1, %2" : "=v"(d) : "v"(fa), "v"(fb));
    return f2h(d);
}
__device__ __forceinline__ h2 pk_add(h2 a, h2 b) {
    float d, fa = h2f(a), fb = h2f(b);
    asm("v_pk_add_f16 %0, %1, %2" : "=v"(d) : "v"(fa), "v"(fb));
    return f2h(d);
}
__device__ __forceinline__ h2 pk_min(h2 a, h2 b) {
    float d, fa = h2f(a), fb = h2f(b);
    asm("v_pk_min_f16 %0, %1, %2" : "=v"(d) : "v"(fa), "v"(fb));
    return f2h(d);
}
__device__ __forceinline__ h2 pk_max(h2 a, h2 b) {
    float d, fa = h2f(a), fb = h2f(b);
    asm("v_pk_max_f16 %0, %1, %2" : "=v"(d) : "v"(fa), "v"(fb));
    return f2h(d);
}
// f32 += a.lo*b.lo + a.hi*b.hi  (dual MAC, f32 accumulate)
__device__ __forceinline__ float pk_dot2(h2 a, h2 b, float c) {
    float d, fa = h2f(a), fb = h2f(b);
    asm("v_dot2_f32_f16 %0, %1, %2, %3" : "=v"(d) : "v"(fa), "v"(fb), "v"(c));
    return d;
}

__device__ __forceinline__ h2 h2c(float x) {
    h2 r; r.x = (_Float16)x; r.y = (_Float16)x; return r;
}
__device__ __forceinline__ h2 h2p(float a, float b) {
    h2 r; r.x = (_Float16)a; r.y = (_Float16)b; return r;
}

struct alignas(16) LWB {           // boundary path: 32 B (R11 layout)
    h2 a0, a1, a2, a3;             // W1 rows 0..3
    h2 kLR, kUD;                   // b1 + ea.W1[4:6]
    h2 c0, c1;                     // cscale * W2 row (dup)
};
struct alignas(16) LWI {           // interior path: 32 B
    h2 a0, a2;                     // W1 rows 0,2
    h2 kLR, kUD;                   // b1 + ea.W1[4:6] + 4*(a1+a3) folded
    h2 c00, c11;                   // cscale * W2 (dup per comp)
    h2 pad0, pad1;
};

// Swizzle: unit t = part*JPT + jj -> slot jj*SPLIT + part (quad-consecutive,
// broadcast-conflict-free). cscale = LAM for grad3, 1 for final.
__device__ __forceinline__ void fill_lds(LWB* lwB, LWI* lwI, float cscale,
                                         const float* __restrict__ W1,
                                         const float* __restrict__ b1,
                                         const float* __restrict__ W2,
                                         const float* __restrict__ b2) {
    const int t = threadIdx.x;
    if (t < HID) {
        const float H = 1.0f / 511.0f;
        float a1f = W1[1 * HID + t], a3f = W1[3 * HID + t];
        float a4 = W1[4 * HID + t], a5 = W1[5 * HID + t];
        float b  = b1[t];
        float kL = b - H * a4, kR = b + H * a4;
        float kU = b - H * a5, kD = b + H * a5;
        float c0f = cscale * W2[2 * t + 0], c1f = cscale * W2[2 * t + 1];
        const int slot = ((t & (JPT - 1)) * SPLIT) | (t / JPT);
        LWB wb;
        wb.a0 = h2c(W1[0 * HID + t]); wb.a1 = h2c(a1f);
        wb.a2 = h2c(W1[2 * HID + t]); wb.a3 = h2c(a3f);
        wb.kLR = h2p(kL, kR); wb.kUD = h2p(kU, kD);
        wb.c0 = h2c(c0f); wb.c1 = h2c(c1f);
        lwB[slot] = wb;
        const float f4 = 4.0f * (a1f + a3f);   // interior: all degrees == 4
        LWI wi;
        wi.a0 = wb.a0; wi.a2 = wb.a2;
        wi.kLR = h2p(kL + f4, kR + f4); wi.kUD = h2p(kU + f4, kD + f4);
        wi.c00 = h2c(c0f); wi.c11 = h2c(c1f);
        wi.pad0 = h2c(0.f); wi.pad1 = h2c(0.f);
        lwI[slot] = wi;
    }
}

// Kernel 1: grad_u, grad_v, grad_p (lambda-Pade[3/2] tanh).
// SoA out: g[0]=gu0 g[1]=gu1 ... g[5]=gp1
__global__ void __launch_bounds__(256) grad3_kernel(
    const float* __restrict__ fields, const float* __restrict__ degrees,
    const float* __restrict__ W1, const float* __restrict__ b1,
    const float* __restrict__ W2, const float* __restrict__ b2,
    float* __restrict__ g)
{
    __shared__ LWB lwB[HID];
    __shared__ LWI lwI[HID];
    fill_lds(lwB, lwI, LAM, W1, b1, W2, b2);
    __syncthreads();

    const int gid  = blockIdx.x * 256 + threadIdx.x;
    const int idx  = gid >> 2;          // node (4 lanes per node)
    const int part = gid & 3;           // hidden-dim slice
    const int brow = blockIdx.x >> 3, bseg = blockIdx.x & 7;
    // rows 2..509: node AND all neighbors have degree 4 (rows 0/511 are deg-3;
    // row-1/510 nodes have deg-3 NEIGHBORS — R12's bug). cols via segs 1..6.
    const bool interior = (brow >= 2) & (brow <= GW - 3) & (bseg >= 1) & (bseg <= 6);

    // Pade[3/2] constants
    const h2 cP = h2c(3.4f), cM = h2c(-3.4f), c27 = h2c(27.f), c9 = h2c(9.f),
             two = h2c(2.f);
    const float b20 = b2[0], b21 = b2[1];

    if (interior) {
        // ---------------- interior fast path ----------------
        h2 s0h[3], sN2[2][3];
        #pragma unroll
        for (int f = 0; f < 3; ++f) s0h[f] = h2c(fields[3 * idx + f]);
        #pragma unroll
        for (int f = 0; f < 3; ++f) {
            sN2[0][f] = h2p(fields[3 * (idx - 1)  + f], fields[3 * (idx + 1)  + f]);
            sN2[1][f] = h2p(fields[3 * (idx - GW) + f], fields[3 * (idx + GW) + f]);
        }
        float acc[3][2];
        #pragma unroll
        for (int f = 0; f < 3; ++f) { acc[f][0] = 0.f; acc[f][1] = 0.f; }

        const LWI* lwp = lwI + part;
        #pragma unroll 2
        for (int jj = 0; jj < JPT; ++jj) {
            LWI w = lwp[jj * SPLIT];
            #pragma unroll
            for (int f = 0; f < 3; ++f) {
                h2 pf = pk_mul(s0h[f], w.a0);
                #pragma unroll
                for (int dp = 0; dp < 2; ++dp) {
                    h2 kk  = dp ? w.kUD : w.kLR;
                    h2 hh  = pk_fma(sN2[dp][f], w.a2, pk_add(kk, pf));
                    h2 t   = pk_min(cP, pk_max(cM, hh));
                    h2 s   = pk_mul(t, t);
                    h2 num = pk_mul(t, pk_add(s, c27));
                    h2 den = pk_fma(s, c9, c27);
                    unsigned int db = __builtin_bit_cast(unsigned int, den);
                    h2 r0  = __builtin_bit_cast(h2, 0x77987798u - db);
                    h2 rr  = pk_mul(r0, pk_nfma(den, r0, two));
                    h2 th  = pk_mul(num, rr);
                    acc[f][0] = pk_dot2(th, w.c00, acc[f][0]);
                    acc[f][1] = pk_dot2(th, w.c11, acc[f][1]);
                }
            }
        }
        #pragma unroll
        for (int f = 0; f < 3; ++f) {
            #pragma unroll
            for (int c = 0; c < 2; ++c) {
                float s = acc[f][c];
                s += __shfl_xor(s, 1);
                s += __shfl_xor(s, 2);
                if (part == 0)
                    g[(2 * f + c) * GN + idx] = __builtin_fmaf(s, 0.25f, c ? b21 : b20);
            }
        }
    } else {
        // ---------------- boundary path (R11) ----------------
        const int row = idx >> 9, col = idx & (GW - 1);
        const bool vE0 = col > 0, vE1 = col < GW - 1, vE2 = row > 0, vE3 = row < GW - 1;
        int nb[4];
        nb[0] = vE0 ? idx - 1  : idx;
        nb[1] = vE1 ? idx + 1  : idx;
        nb[2] = vE2 ? idx - GW : idx;
        nb[3] = vE3 ? idx + GW : idx;

        h2 s0h[3], sN2[2][3];
        #pragma unroll
        for (int f = 0; f < 3; ++f) s0h[f] = h2c(fields[3 * idx + f]);
        #pragma unroll
        for (int f = 0; f < 3; ++f) {
            sN2[0][f] = h2p(fields[3 * nb[0] + f], fields[3 * nb[1] + f]);
            sN2[1][f] = h2p(fields[3 * nb[2] + f], fields[3 * nb[3] + f]);
        }
        h2 dnbLR = h2p(degrees[nb[0]], degrees[nb[1]]);
        h2 dnbUD = h2p(degrees[nb[2]], degrees[nb[3]]);
        const float dN = degrees[idx];
        const h2 dNh = h2c(dN);

        h2 acc[2][3][2];
        #pragma unroll
        for (int dp = 0; dp < 2; ++dp)
            #pragma unroll
            for (int f = 0; f < 3; ++f) { acc[dp][f][0] = h2c(0.f); acc[dp][f][1] = h2c(0.f); }

        const LWB* lwp = lwB + part;
        #pragma unroll 2
        for (int jj = 0; jj < JPT; ++jj) {
            LWB w = lwp[jj * SPLIT];
            h2 dn1 = pk_mul(dNh, w.a1);
            h2 hb[2];
            hb[0] = pk_fma(dnbLR, w.a3, pk_add(w.kLR, dn1));
            hb[1] = pk_fma(dnbUD, w.a3, pk_add(w.kUD, dn1));
            #pragma unroll
            for (int f = 0; f < 3; ++f) {
                #pragma unroll
                for (int dp = 0; dp < 2; ++dp) {
                    h2 hh  = pk_fma(sN2[dp][f], w.a2, pk_fma(s0h[f], w.a0, hb[dp]));
                    h2 t   = pk_min(cP, pk_max(cM, hh));
                    h2 s   = pk_mul(t, t);
                    h2 num = pk_mul(t, pk_add(s, c27));
                    h2 den = pk_fma(s, c9, c27);
                    unsigned int db = __builtin_bit_cast(unsigned int, den);
                    h2 r0  = __builtin_bit_cast(h2, 0x77987798u - db);
                    h2 rr  = pk_mul(r0, pk_nfma(den, r0, two));
                    h2 th  = pk_mul(num, rr);
                    acc[dp][f][0] = pk_fma(th, w.c0, acc[dp][f][0]);
                    acc[dp][f][1] = pk_fma(th, w.c1, acc[dp][f][1]);
                }
            }
        }
        const float rd = __builtin_amdgcn_rcpf(dN);
        #pragma unroll
        for (int f = 0; f < 3; ++f) {
            #pragma unroll
            for (int c = 0; c < 2; ++c) {
                float s = 0.f;
                s += vE0 ? (float)acc[0][f][c].x : 0.f;
                s += vE1 ? (float)acc[0][f][c].y : 0.f;
                s += vE2 ? (float)acc[1][f][c].x : 0.f;
                s += vE3 ? (float)acc[1][f][c].y : 0.f;
                s += __shfl_xor(s, 1);
                s += __shfl_xor(s, 2);
                if (part == 0)
                    g[(2 * f + c) * GN + idx] = __builtin_fmaf(s, rd, c ? b21 : b20);
            }
        }
    }
}

// Kernel 2: second-order g (damped by NU=0.01 -> cubic activation) + combine.
__global__ void __launch_bounds__(256) final_kernel(
    const float* __restrict__ fields, const float* __restrict__ degrees,
    const float* __restrict__ W1, const float* __restrict__ b1,
    const float* __restrict__ W2, const float* __restrict__ b2,
    const float* __restrict__ g, float* __restrict__ out)
{
    __shared__ LWB lwB[HID];
    __shared__ LWI lwI[HID];
    fill_lds(lwB, lwI, 1.0f, W1, b1, W2, b2);
    __syncthreads();

    const int gid  = blockIdx.x * 256 + threadIdx.x;
    const int idx  = gid >> 2;
    const int part = gid & 3;
    const int brow = blockIdx.x >> 3, bseg = blockIdx.x & 7;
    const bool interior = (brow >= 2) & (brow <= GW - 3) & (bseg >= 1) & (bseg <= 6);

    // cubic tanh: t = clamp(h,+-2); th = t*(0.75 - 0.0625 t^2)
    const h2 cP = h2c(2.0f), cM = h2c(-2.0f), cA = h2c(0.75f), cB = h2c(-0.0625f);

    float s0[4];
    #pragma unroll
    for (int f = 0; f < 4; ++f) s0[f] = g[f * GN + idx];
    h2 s0h[4];
    #pragma unroll
    for (int f = 0; f < 4; ++f) s0h[f] = h2c(s0[f]);

    float r[4];

    if (interior) {
        // ---------------- interior fast path ----------------
        h2 sN2[2][4];
        #pragma unroll
        for (int f = 0; f < 4; ++f) {
            sN2[0][f] = h2p(g[f * GN + idx - 1],  g[f * GN + idx + 1]);
            sN2[1][f] = h2p(g[f * GN + idx - GW], g[f * GN + idx + GW]);
        }
        float acc[4];
        #pragma unroll
        for (int f = 0; f < 4; ++f) acc[f] = 0.f;

        const LWI* lwp = lwI + part;
        #pragma unroll 2
        for (int jj = 0; jj < JPT; ++jj) {
            LWI w = lwp[jj * SPLIT];
            #pragma unroll
            for (int f = 0; f < 4; ++f) {
                h2 pf = pk_mul(s0h[f], w.a0);
                h2 cc = (f & 1) ? w.c11 : w.c00;
                #pragma unroll
                for (int dp = 0; dp < 2; ++dp) {
                    h2 kk = dp ? w.kUD : w.kLR;
                    h2 hh = pk_fma(sN2[dp][f], w.a2, pk_add(kk, pf));
                    h2 t  = pk_min(cP, pk_max(cM, hh));
                    h2 th = pk_mul(t, pk_fma(pk_mul(t, t), cB, cA));
                    acc[f] = pk_dot2(th, cc, acc[f]);
                }
            }
        }
        #pragma unroll
        for (int f = 0; f < 4; ++f) {
            float s = acc[f];
            s += __shfl_xor(s, 1);
            s += __shfl_xor(s, 2);
            r[f] = __builtin_fmaf(s, 0.25f, b2[f & 1]);
        }
    } else {
        // ---------------- boundary path (R11) ----------------
        const int row = idx >> 9, col = idx & (GW - 1);
        const bool vE0 = col > 0, vE1 = col < GW - 1, vE2 = row > 0, vE3 = row < GW - 1;
        int nb[4];
        nb[0] = vE0 ? idx - 1  : idx;
        nb[1] = vE1 ? idx + 1  : idx;
        nb[2] = vE2 ? idx - GW : idx;
        nb[3] = vE3 ? idx + GW : idx;

        h2 sN2[2][4];
        #pragma unroll
        for (int f = 0; f < 4; ++f) {
            sN2[0][f] = h2p(g[f * GN + nb[0]], g[f * GN + nb[1]]);
            sN2[1][f] = h2p(g[f * GN + nb[2]], g[f * GN + nb[3]]);
        }
        h2 dnbLR = h2p(degrees[nb[0]], degrees[nb[1]]);
        h2 dnbUD = h2p(degrees[nb[2]], degrees[nb[3]]);
        const float dN = degrees[idx];
        const h2 dNh = h2c(dN);

        h2 acc[2][4];
        #pragma unroll
        for (int dp = 0; dp < 2; ++dp)
            #pragma unroll
            for (int f = 0; f < 4; ++f) acc[dp][f] = h2c(0.f);

        const LWB* lwp = lwB + part;
        #pragma unroll 2
        for (int jj = 0; jj < JPT; ++jj) {
            LWB w = lwp[jj * SPLIT];
            h2 dn1 = pk_mul(dNh, w.a1);
            h2 hb[2];
            hb[0] = pk_fma(dnbLR, w.a3, pk_add(w.kLR, dn1));
            hb[1] = pk_fma(dnbUD, w.a3, pk_add(w.kUD, dn1));
            #pragma unroll
            for (int f = 0; f < 4; ++f) {
                h2 cc = (f & 1) ? w.c1 : w.c0;
                #pragma unroll
                for (int dp = 0; dp < 2; ++dp) {
                    h2 hh = pk_fma(sN2[dp][f], w.a2, pk_fma(s0h[f], w.a0, hb[dp]));
                    h2 t  = pk_min(cP, pk_max(cM, hh));
                    h2 th = pk_mul(t, pk_fma(pk_mul(t, t), cB, cA));
                    acc[dp][f] = pk_fma(th, cc, acc[dp][f]);
                }
            }
        }
        const float rd = __builtin_amdgcn_rcpf(dN);
        #pragma unroll
        for (int f = 0; f < 4; ++f) {
            float s = 0.f;
            s += vE0 ? (float)acc[0][f].x : 0.f;
            s += vE1 ? (float)acc[0][f].y : 0.f;
            s += vE2 ? (float)acc[1][f].x : 0.f;
            s += vE3 ? (float)acc[1][f].y : 0.f;
            s += __shfl_xor(s, 1);
            s += __shfl_xor(s, 2);
            r[f] = __builtin_fmaf(s, rd, b2[f & 1]);
        }
    }

    if (part == 0) {
        const float lap_u = r[0] + r[1];   // grad_ux[:,0] + grad_uy[:,1]
        const float lap_v = r[2] + r[3];   // grad_vx[:,0] + grad_vy[:,1]
        const float u = fields[3 * idx + 0], v = fields[3 * idx + 1];
        const float gu0 = s0[0], gu1 = s0[1], gv0 = s0[2], gv1 = s0[3];
        const float gp0 = g[4 * GN + idx], gp1 = g[5 * GN + idx];
        out[3 * idx + 0] = gu0 + gv1;                                // continuity
        out[3 * idx + 1] = u * gu0 + v * gu1 + gp0 - NUC * lap_u;    // mom_x
        out[3 * idx + 2] = u * gv0 + v * gv1 + gp1 - NUC * lap_v;    // mom_y
    }
}

extern "C" void kernel_launch(void* const* d_in, const int* in_sizes, int n_in,
                              void* d_out, int out_size, void* d_ws, size_t ws_size,
                              hipStream_t stream) {
    const float* fields  = (const float*)d_in[0];
    const float* degrees = (const float*)d_in[1];
    const float* W1 = (const float*)d_in[3];
    const float* b1 = (const float*)d_in[4];
    const float* W2 = (const float*)d_in[5];
    const float* b2 = (const float*)d_in[6];
    float* g   = (float*)d_ws;           // 6 * GN floats = 6.3 MB scratch
    float* out = (float*)d_out;

    const int blocks = (GN * SPLIT) / 256;   // 4096
    grad3_kernel<<<blocks, 256, 0, stream>>>(fields, degrees, W1, b1, W2, b2, g);
    final_kernel<<<blocks, 256, 0, stream>>>(fields, degrees, W1, b1, W2, b2, g, out);
}

// Round 15
// 160.273 us; speedup vs baseline: 1.0112x; 1.0112x over previous
//
#include <hip/hip_runtime.h>

// Grid: 512x512 nodes, idx = row*512 + col. h = 1/511.
// m_in = [s_dst, deg_dst, s_src, deg_src, ea_x, ea_y] @ W1 -> tanh -> @ W2
// g(s)[n] = (1/deg_n) * sum_incoming(msg) + b2
//
// R14: consolidation at the measured optimum (= R10 config, fastest clean
// structure with 2x error headroom). Evidence across R0-R13:
//  - issue floor ~4.3 cy/wave-instr regardless of op type (pk f16 = pk f32 =
//    scalar throughput); trans ~2.5x; instruction count is the only currency.
//  - grad3 (undamped outputs): exp-trick sigmoid tanh(h)=1-2/(1+e^{2h}),
//    2log2(e) folded into W1/b1, "1-2*" + sum_j c_j folded into epilogue,
//    f16 magic recip + 1 Newton. absmax 0.125.
//  - final (outputs damped by NU=0.01): Hermite cubic t(0.75-0.0625t^2),
//    t=clamp(h,+-2) — err 0.1 -> <=0.006 after damping.
//  - SPLIT=4 hidden-slicing, swizzled single LDS weight table (broadcast,
//    ~458k conflict cy; R13's dual-table variant doubled conflicts, regressed).
//  - fusion (R7) and interior specialization (R12/R13) both regressed/neutral.

#define GW    512
#define GN    (GW * GW)
#define HID   64
#define SPLIT 4
#define JPT   (HID / SPLIT)    // 16 hidden units per thread
#define NUC   0.01f
#define FSC   2.8853900817779268f   // 2*log2(e)

typedef _Float16 h2 __attribute__((ext_vector_type(2)));

__device__ __forceinline__ float h2f(h2 x) { return __builtin_bit_cast(float, x); }
__device__ __forceinline__ h2 f2h(float x) { return __builtin_bit_cast(h2, x); }

// Inline-asm packed f16 helpers (clang won't form v_pk_* from ext_vector on
// gfx950 — R3 vs R4 evidence). Operands proxied as 32-bit floats.
__device__ __forceinline__ h2 pk_fma(h2 a, h2 b, h2 c) {
    float d, fa = h2f(a), fb = h2f(b), fc = h2f(c);
    asm("v_pk_fma_f16 %0, %1, %2, %3" : "=v"(d) : "v"(fa), "v"(fb), "v"(fc));
    return f2h(d);
}
__device__ __forceinline__ h2 pk_nfma(h2 a, h2 b, h2 c) {   // (-a)*b + c
    float d, fa = h2f(a), fb = h2f(b), fc = h2f(c);
    asm("v_pk_fma_f16 %0, %1, %2, %3 neg_lo:[1,0,0] neg_hi:[1,0,0]"
        : "=v"(d) : "v"(fa), "v"(fb), "v"(fc));
    return f2h(d);
}
__device__ __forceinline__ h2 pk_mul(h2 a, h2 b) {
    float d, fa = h2f(a), fb = h2f(b);
    asm("v_pk_mul_f16 %0, %1, %2" : "=v"(d) : "v"(fa), "v"(fb));
    return f2h(d);
}
__device__ __forceinline__ h2 pk_add(h2 a, h2 b) {
    float d, fa = h2f(a), fb = h2f(b);
    asm("v_pk_add_f16 %0, %1, %2" : "=v"(d) : "v"(fa), "v"(fb));
    return f2h(d);
}
__device__ __forceinline__ h2 pk_min(h2 a, h2 b) {
    float d, fa = h2f(a), fb = h2f(b);
    asm("v_pk_min_f16 %0, %1, %2" : "=v"(d) : "v"(fa), "v"(fb));
    return f2h(d);
}
__device__ __forceinline__ h2 pk_max(h2 a, h2 b) {
    float d, fa = h2f(a), fb = h2f(b);
    asm("v_pk_max_f16 %0, %1, %2" : "=v"(d) : "v"(fa), "v"(fb));
    return f2h(d);
}

__device__ __forceinline__ h2 h2c(float x) {
    h2 r; r.x = (_Float16)x; r.y = (_Float16)x; return r;
}
__device__ __forceinline__ h2 h2p(float a, float b) {
    h2 r; r.x = (_Float16)a; r.y = (_Float16)b; return r;
}

// r ~= 1/(1+e), e = 2^hc, hc pre-clamped so den in [1, 4097] (magic-safe).
// tanh = 1 - 2r, handled in the epilogue.
__device__ __forceinline__ h2 sigr(h2 hc, h2 one, h2 two) {
    h2 e   = __builtin_elementwise_exp2(hc);     // 2x v_exp_f16
    h2 den = pk_add(e, one);
    unsigned int db = __builtin_bit_cast(unsigned int, den);
    h2 r0  = __builtin_bit_cast(h2, 0x77987798u - db);   // magic seed
    return pk_mul(r0, pk_nfma(den, r0, two));            // 1 Newton
}

struct alignas(16) LWH {           // 32 B per hidden unit, broadcast pairs
    h2 a0, a1, a2, a3;             // (scaled) W1 rows 0..3 (dup both halves)
    h2 kLR, kUD;                   // scaled (b1 + ea.W1[4:6]) per incoming dir
    h2 c0, c1;                     // W2 row (dup)
};

// Swizzle: unit t = part*JPT + jj -> slot jj*SPLIT + part (quad-consecutive,
// broadcast-conflict-free). scale=FSC for grad3 (exp-trick), 1 for final.
// sCb[c] = sum_j W2[j][c] + b2[c] (grad3 epilogue constant).
__device__ __forceinline__ void fill_lds(LWH* lw, float* sCb, float scale,
                                         const float* __restrict__ W1,
                                         const float* __restrict__ b1,
                                         const float* __restrict__ W2,
                                         const float* __restrict__ b2) {
    const int t = threadIdx.x;
    if (t < HID) {                 // threads 0..63 == wave 0 exactly
        const float H = 1.0f / 511.0f;
        float a4 = W1[4 * HID + t], a5 = W1[5 * HID + t];
        float b  = b1[t];
        float c0f = W2[2 * t + 0], c1f = W2[2 * t + 1];
        LWH w;
        w.a0 = h2c(scale * W1[0 * HID + t]); w.a1 = h2c(scale * W1[1 * HID + t]);
        w.a2 = h2c(scale * W1[2 * HID + t]); w.a3 = h2c(scale * W1[3 * HID + t]);
        w.kLR = h2p(scale * (b - H * a4), scale * (b + H * a4));
        w.kUD = h2p(scale * (b - H * a5), scale * (b + H * a5));
        w.c0 = h2c(c0f);  w.c1 = h2c(c1f);
        const int slot = ((t & (JPT - 1)) * SPLIT) | (t / JPT);
        lw[slot] = w;
        float v0 = c0f, v1 = c1f;
        #pragma unroll
        for (int off = 1; off < 64; off <<= 1) {
            v0 += __shfl_xor(v0, off);
            v1 += __shfl_xor(v1, off);
        }
        if (t == 0) { sCb[0] = v0 + b2[0]; sCb[1] = v1 + b2[1]; }
    }
}

// Kernel 1: grad_u, grad_v, grad_p (UNDAMPED -> accurate exp-sigmoid path).
// SoA out: g[0]=gu0 g[1]=gu1 ... g[5]=gp1
__global__ void __launch_bounds__(256) grad3_kernel(
    const float* __restrict__ fields, const float* __restrict__ degrees,
    const float* __restrict__ W1, const float* __restrict__ b1,
    const float* __restrict__ W2, const float* __restrict__ b2,
    float* __restrict__ g)
{
    __shared__ LWH lw[HID];
    __shared__ float sCb[2];
    fill_lds(lw, sCb, FSC, W1, b1, W2, b2);
    __syncthreads();

    const int gid  = blockIdx.x * 256 + threadIdx.x;
    const int idx  = gid >> 2;          // node (4 lanes per node)
    const int part = gid & 3;           // hidden-dim slice
    const int row = idx >> 9, col = idx & (GW - 1);
    const bool vE0 = col > 0, vE1 = col < GW - 1, vE2 = row > 0, vE3 = row < GW - 1;
    int nb[4];
    nb[0] = vE0 ? idx - 1  : idx;
    nb[1] = vE1 ? idx + 1  : idx;
    nb[2] = vE2 ? idx - GW : idx;
    nb[3] = vE3 ? idx + GW : idx;

    const h2 one = h2c(1.f), two = h2c(2.f), hcl = h2c(12.0f);

    h2 s0h[3];
    #pragma unroll
    for (int f = 0; f < 3; ++f) s0h[f] = h2c(fields[3 * idx + f]);
    h2 sN2[2][3];                       // [pair LR/UD][field]
    #pragma unroll
    for (int f = 0; f < 3; ++f) {
        sN2[0][f] = h2p(fields[3 * nb[0] + f], fields[3 * nb[1] + f]);
        sN2[1][f] = h2p(fields[3 * nb[2] + f], fields[3 * nb[3] + f]);
    }
    h2 dnbLR = h2p(degrees[nb[0]], degrees[nb[1]]);
    h2 dnbUD = h2p(degrees[nb[2]], degrees[nb[3]]);
    const float dN = degrees[idx];
    const h2 dNh = h2c(dN);

    h2 acc[2][3][2];                    // [pair][field][W2 comp], sum c*r
    #pragma unroll
    for (int dp = 0; dp < 2; ++dp)
        #pragma unroll
        for (int f = 0; f < 3; ++f) { acc[dp][f][0] = h2c(0.f); acc[dp][f][1] = h2c(0.f); }

    const LWH* lwp = lw + part;         // quad-consecutive slots
    #pragma unroll 2
    for (int jj = 0; jj < JPT; ++jj) {
        LWH w = lwp[jj * SPLIT];
        h2 dn1 = pk_mul(dNh, w.a1);
        h2 hb[2];
        hb[0] = pk_fma(dnbLR, w.a3, pk_add(w.kLR, dn1));
        hb[1] = pk_fma(dnbUD, w.a3, pk_add(w.kUD, dn1));
        #pragma unroll
        for (int f = 0; f < 3; ++f) {
            #pragma unroll
            for (int dp = 0; dp < 2; ++dp) {
                h2 hh = pk_fma(sN2[dp][f], w.a2, pk_fma(s0h[f], w.a0, hb[dp]));
                h2 r  = sigr(pk_min(hcl, hh), one, two);
                acc[dp][f][0] = pk_fma(r, w.c0, acc[dp][f][0]);
                acc[dp][f][1] = pk_fma(r, w.c1, acc[dp][f][1]);
            }
        }
    }

    const float m2rd = -2.0f * __builtin_amdgcn_rcpf(dN);
    #pragma unroll
    for (int f = 0; f < 3; ++f) {
        #pragma unroll
        for (int c = 0; c < 2; ++c) {
            float s = 0.f;
            s += vE0 ? (float)acc[0][f][c].x : 0.f;
            s += vE1 ? (float)acc[0][f][c].y : 0.f;
            s += vE2 ? (float)acc[1][f][c].x : 0.f;
            s += vE3 ? (float)acc[1][f][c].y : 0.f;
            s += __shfl_xor(s, 1);
            s += __shfl_xor(s, 2);
            if (part == 0)   // sum_d valid = dN: (dN*C - 2s)/dN + b2 == fma
                g[(2 * f + c) * GN + idx] = __builtin_fmaf(s, m2rd, sCb[c]);
        }
    }
}

// Kernel 2: second-order g (outputs damped by NU=0.01 -> cubic activation)
// + NS combine.
__global__ void __launch_bounds__(256) final_kernel(
    const float* __restrict__ fields, const float* __restrict__ degrees,
    const float* __restrict__ W1, const float* __restrict__ b1,
    const float* __restrict__ W2, const float* __restrict__ b2,
    const float* __restrict__ g, float* __restrict__ out)
{
    __shared__ LWH lw[HID];
    __shared__ float sCb[2];
    fill_lds(lw, sCb, 1.0f, W1, b1, W2, b2);   // raw weights
    __syncthreads();

    const int gid  = blockIdx.x * 256 + threadIdx.x;
    const int idx  = gid >> 2;
    const int part = gid & 3;
    const int row = idx >> 9, col = idx & (GW - 1);
    const bool vE0 = col > 0, vE1 = col < GW - 1, vE2 = row > 0, vE3 = row < GW - 1;
    int nb[4];
    nb[0] = vE0 ? idx - 1  : idx;
    nb[1] = vE1 ? idx + 1  : idx;
    nb[2] = vE2 ? idx - GW : idx;
    nb[3] = vE3 ? idx + GW : idx;

    // cubic tanh: t = clamp(h,+-2); th = t*(0.75 - 0.0625 t^2)
    const h2 cP = h2c(2.0f), cM = h2c(-2.0f), cA = h2c(0.75f), cB = h2c(-0.0625f);

    float s0[4];
    #pragma unroll
    for (int f = 0; f < 4; ++f) s0[f] = g[f * GN + idx];
    h2 s0h[4];
    #pragma unroll
    for (int f = 0; f < 4; ++f) s0h[f] = h2c(s0[f]);
    h2 sN2[2][4];
    #pragma unroll
    for (int f = 0; f < 4; ++f) {
        sN2[0][f] = h2p(g[f * GN + nb[0]], g[f * GN + nb[1]]);
        sN2[1][f] = h2p(g[f * GN + nb[2]], g[f * GN + nb[3]]);
    }
    h2 dnbLR = h2p(degrees[nb[0]], degrees[nb[1]]);
    h2 dnbUD = h2p(degrees[nb[2]], degrees[nb[3]]);
    const float dN = degrees[idx];
    const h2 dNh = h2c(dN);

    h2 acc[2][4];                       // [pair][field], sum c*th
    #pragma unroll
    for (int dp = 0; dp < 2; ++dp)
        #pragma unroll
        for (int f = 0; f < 4; ++f) acc[dp][f] = h2c(0.f);

    const LWH* lwp = lw + part;
    #pragma unroll 2
    for (int jj = 0; jj < JPT; ++jj) {
        LWH w = lwp[jj * SPLIT];
        h2 dn1 = pk_mul(dNh, w.a1);
        h2 hb[2];
        hb[0] = pk_fma(dnbLR, w.a3, pk_add(w.kLR, dn1));
        hb[1] = pk_fma(dnbUD, w.a3, pk_add(w.kUD, dn1));
        #pragma unroll
        for (int f = 0; f < 4; ++f) {
            h2 cc = (f & 1) ? w.c1 : w.c0;   // needed comp: 0,1,0,1
            #pragma unroll
            for (int dp = 0; dp < 2; ++dp) {
                h2 hh = pk_fma(sN2[dp][f], w.a2, pk_fma(s0h[f], w.a0, hb[dp]));
                h2 t  = pk_min(cP, pk_max(cM, hh));
                h2 th = pk_mul(t, pk_fma(pk_mul(t, t), cB, cA));
                acc[dp][f] = pk_fma(th, cc, acc[dp][f]);
            }
        }
    }

    const float rd = __builtin_amdgcn_rcpf(dN);
    float r[4];
    #pragma unroll
    for (int f = 0; f < 4; ++f) {
        float s = 0.f;
        s += vE0 ? (float)acc[0][f].x : 0.f;
        s += vE1 ? (float)acc[0][f].y : 0.f;
        s += vE2 ? (float)acc[1][f].x : 0.f;
        s += vE3 ? (float)acc[1][f].y : 0.f;
        s += __shfl_xor(s, 1);
        s += __shfl_xor(s, 2);
        r[f] = __builtin_fmaf(s, rd, b2[f & 1]);
    }

    if (part == 0) {
        const float lap_u = r[0] + r[1];   // grad_ux[:,0] + grad_uy[:,1]
        const float lap_v = r[2] + r[3];   // grad_vx[:,0] + grad_vy[:,1]
        const float u = fields[3 * idx + 0], v = fields[3 * idx + 1];
        const float gu0 = s0[0], gu1 = s0[1], gv0 = s0[2], gv1 = s0[3];
        const float gp0 = g[4 * GN + idx], gp1 = g[5 * GN + idx];
        out[3 * idx + 0] = gu0 + gv1;                                // continuity
        out[3 * idx + 1] = u * gu0 + v * gu1 + gp0 - NUC * lap_u;    // mom_x
        out[3 * idx + 2] = u * gv0 + v * gv1 + gp1 - NUC * lap_v;    // mom_y
    }
}

extern "C" void kernel_launch(void* const* d_in, const int* in_sizes, int n_in,
                              void* d_out, int out_size, void* d_ws, size_t ws_size,
                              hipStream_t stream) {
    const float* fields  = (const float*)d_in[0];
    const float* degrees = (const float*)d_in[1];
    const float* W1 = (const float*)d_in[3];
    const float* b1 = (const float*)d_in[4];
    const float* W2 = (const float*)d_in[5];
    const float* b2 = (const float*)d_in[6];
    float* g   = (float*)d_ws;           // 6 * GN floats = 6.3 MB scratch
    float* out = (float*)d_out;

    const int blocks = (GN * SPLIT) / 256;   // 4096
    grad3_kernel<<<blocks, 256, 0, stream>>>(fields, degrees, W1, b1, W2, b2, g);
    final_kernel<<<blocks, 256, 0, stream>>>(fields, degrees, W1, b1, W2, b2, g, out);
}